// Round 4
// baseline (1992.600 us; speedup 1.0000x reference)
//
#include <hip/hip_runtime.h>
#include <math.h>

// F=4, T=12, C=512, HID=256, OUT=12
#define NF 48
#define TT 12

typedef __bf16 v8bf __attribute__((ext_vector_type(8)));
typedef float v4f __attribute__((ext_vector_type(4)));

// ---------------- small prep kernels ----------------

__global__ void k_init_deg(float* __restrict__ deg, int n) {
  int i = blockIdx.x * blockDim.x + threadIdx.x;
  if (i < n) deg[i] = 1.0f;
}

__global__ void k_scatter_deg(const int* __restrict__ dst, const float* __restrict__ w,
                              float* __restrict__ deg, int e) {
  int i = blockIdx.x * blockDim.x + threadIdx.x;
  if (i < e) atomicAdd(&deg[dst[i]], w[i]);
}

__global__ void k_dinv(const float* __restrict__ deg, float* __restrict__ dinv, int n) {
  int i = blockIdx.x * blockDim.x + threadIdx.x;
  if (i < n) dinv[i] = rsqrtf(fmaxf(deg[i], 1e-12f));
}

__global__ void k_zero(float* __restrict__ p, int n) {
  int i = blockIdx.x * blockDim.x + threadIdx.x;
  if (i < n) p[i] = 0.f;
}

__global__ void k_zeroi(int* __restrict__ p, int n) {
  int i = blockIdx.x * blockDim.x + threadIdx.x;
  if (i < n) p[i] = 0;
}

// ---------------- CSR build (by dst) ----------------

__global__ void k_count(const int* __restrict__ dst, int* __restrict__ cnt, int e) {
  int i = blockIdx.x * blockDim.x + threadIdx.x;
  if (i < e) atomicAdd(&cnt[dst[i]], 1);
}

__global__ void k_scan(const int* __restrict__ cnt, int* __restrict__ offs, int n) {
  __shared__ int s[1024];
  __shared__ int carry;
  int tid = threadIdx.x;
  if (tid == 0) carry = 0;
  __syncthreads();
  for (int base = 0; base < n; base += 1024) {
    int v = (base + tid < n) ? cnt[base + tid] : 0;
    s[tid] = v;
    __syncthreads();
    for (int off = 1; off < 1024; off <<= 1) {
      int t = 0;
      if (tid >= off) t = s[tid - off];
      __syncthreads();
      s[tid] += t;
      __syncthreads();
    }
    if (base + tid < n) offs[base + tid] = carry + s[tid] - v;
    __syncthreads();
    if (tid == 0) carry += s[1023];
    __syncthreads();
  }
  if (tid == 0) offs[n] = carry;
}

__global__ void k_place(const int* __restrict__ src, const int* __restrict__ dst,
                        const float* __restrict__ w, const int* __restrict__ offs,
                        int* __restrict__ fill, int* __restrict__ csrc,
                        float* __restrict__ cw, int e) {
  int i = blockIdx.x * blockDim.x + threadIdx.x;
  if (i >= e) return;
  int d = dst[i];
  int p = offs[d] + atomicAdd(&fill[d], 1);
  csrc[p] = src[i];
  cw[p] = w[i];
}

__global__ void k_gather(const int* __restrict__ offs, const int* __restrict__ csrc,
                         const float* __restrict__ cw, const float* __restrict__ dinv,
                         const float* __restrict__ x, float* __restrict__ Y, int n) {
  int tg = blockIdx.x * blockDim.x + threadIdx.x;
  if (tg >= n * 12) return;
  int i = tg / 12, q = tg % 12;
  float di = dinv[i];
  const float4* x4 = (const float4*)x;
  float4 sv = x4[(size_t)i * 12 + q];
  float ax = di * sv.x, ay = di * sv.y, az = di * sv.z, aw = di * sv.w;
  int e1 = offs[i + 1];
  for (int e = offs[i]; e < e1; e++) {
    int s = csrc[e];
    float wv = cw[e] * dinv[s];
    float4 xv = x4[(size_t)s * 12 + q];
    ax = fmaf(wv, xv.x, ax); ay = fmaf(wv, xv.y, ay);
    az = fmaf(wv, xv.z, az); aw = fmaf(wv, xv.w, aw);
  }
  float4 o = make_float4(di * ax, di * ay, di * az, di * aw);
  ((float4*)Y)[(size_t)i * 12 + q] = o;
}

// ---------------- weight prep ----------------

__global__ void k_t_zr(const float* __restrict__ Wzl, const float* __restrict__ Wrl,
                       __bf16* __restrict__ WT) {
  int idx = blockIdx.x * blockDim.x + threadIdx.x;
  if (idx >= 1024 * 512) return;
  int c = idx >> 9, k = idx & 511;
  float v = (c < 512) ? Wzl[(512 + k) * 512 + c] : Wrl[(512 + k) * 512 + (c - 512)];
  WT[idx] = (__bf16)v;
}

__global__ void k_t_h(const float* __restrict__ Whl, __bf16* __restrict__ WT) {
  int idx = blockIdx.x * blockDim.x + threadIdx.x;
  if (idx >= 512 * 512) return;
  int c = idx >> 9, k = idx & 511;
  WT[idx] = (__bf16)Whl[(512 + k) * 512 + c];
}

__global__ void k_t_1(const float* __restrict__ W1, __bf16* __restrict__ WT) {
  int idx = blockIdx.x * blockDim.x + threadIdx.x;
  if (idx >= 256 * 512) return;
  int c = idx >> 9, k = idx & 511;
  WT[idx] = (__bf16)W1[k * 256 + c];
}

__global__ void k_build_eff(const float* __restrict__ Wg, const float* __restrict__ Wl,
                            const float* __restrict__ bg, const float* __restrict__ bl,
                            float* __restrict__ Weff, float* __restrict__ beff,
                            int ostride, int ooff) {
  int idx = blockIdx.x * blockDim.x + threadIdx.x;
  if (idx >= 5 * 512) return;
  int r = idx / 512, c = idx % 512;
  float s = 0.f;
  if (r < 4) {
    for (int k = 0; k < 512; k++) s += Wg[r * 512 + k] * Wl[k * 512 + c];
    Weff[r * ostride + ooff + c] = s;
  } else {
    for (int k = 0; k < 512; k++) s += bg[k] * Wl[k * 512 + c];
    beff[ooff + c] = s + bl[c];
  }
}

__global__ void k_softmax_att(const float* __restrict__ att, float* __restrict__ probs) {
  if (blockIdx.x == 0 && threadIdx.x == 0) {
    float m = -1e30f;
    for (int t = 0; t < TT; t++) m = fmaxf(m, att[t]);
    float e[TT], s = 0.f;
    for (int t = 0; t < TT; t++) { e[t] = expf(att[t] - m); s += e[t]; }
    for (int t = 0; t < TT; t++) probs[t] = e[t] / s;
  }
}

// ---------------- MFMA GEMM, pipelined ----------------
// C = A[M,512]bf16 @ Bt^T (Bt [Nout,512] bf16). 64-row tiles, BK=32, dbuf LDS,
// single barrier/iter, global loads issued 2 iters ahead.
// MODE 0: A=hist[t].     64x256 tile. epi: sigmoid(pre+Y@Weff+beff) -> Zbf|Rbf
// MODE 1: A=hist[t]*r.   64x128 tile. epi: ht=tanh(..); hn=z*Hold+(1-z)*ht
//                        -> Hn fp32 + hist[t+1] bf16
// MODE 2: A=accRelu.     64x256 tile. epi: relu(pre+b1) -> T1 fp32
template <int MODE>
__global__ __launch_bounds__(256, 2) void k_mm(
    const __bf16* __restrict__ Abf, const __bf16* __restrict__ Bt,
    const __bf16* __restrict__ Rbf, const __bf16* __restrict__ Zbf,
    const float* __restrict__ Hold, const float* __restrict__ Y,
    const float* __restrict__ Weff, const float* __restrict__ beff,
    float* __restrict__ Ofp, __bf16* __restrict__ Obf, __bf16* __restrict__ Obf2,
    int M, int t) {
  constexpr int TN = (MODE == 1) ? 128 : 256;
  constexpr int NoutW = (MODE == 0) ? 1024 : 512;  // Weff row stride (MODE<2 only)
  constexpr int BCH = (MODE == 1) ? 2 : 4;         // B uint4 chunks per thread
  constexpr int MI = (MODE == 1) ? 2 : 4;
  constexpr int LDA = 40;
  __shared__ __bf16 sA[2][64 * LDA];
  __shared__ __bf16 sB[2][TN * LDA];
  const int tid = threadIdx.x;
  const int row0 = blockIdx.x * 64;
  const int col0 = blockIdx.y * TN;
  const int w = tid >> 6, lane = tid & 63, lm = lane & 15, quad = lane >> 4;
  const int wr = (MODE == 1) ? (w >> 1) * 32 : 0;
  const int wc = (MODE == 1) ? (w & 1) * 64 : w * 64;

  // staging coords: A tile 64x32 -> 4 thr/row x 8 elems; B tile TNx32
  const int ar = tid >> 2, ach = (tid & 3) * 8;
  const int arg = row0 + ar;
  const bool aval = arg < M;
  const __bf16* Arow = Abf + (size_t)arg * 512 + ach;
  const __bf16* Rrow = Rbf + (size_t)arg * 512 + ach;  // MODE1 only
  const int br = (MODE == 1) ? (tid >> 1) : tid;
  const int bch0 = (MODE == 1) ? (tid & 1) * 16 : 0;
  const __bf16* Brow = Bt + (size_t)(col0 + br) * 512 + bch0;

  v4f acc4[MI][4];
#pragma unroll
  for (int i = 0; i < MI; i++)
#pragma unroll
    for (int j = 0; j < 4; j++) acc4[i][j] = (v4f){0.f, 0.f, 0.f, 0.f};

  v8bf rh, rr;
  uint4 rb[BCH];

  auto gload = [&](int k0) {
    if (aval) {
      rh = *(const v8bf*)(Arow + k0);
      if constexpr (MODE == 1) rr = *(const v8bf*)(Rrow + k0);
    } else {
      v8bf z;
#pragma unroll
      for (int j = 0; j < 8; j++) z[j] = (__bf16)0.f;
      rh = z;
      if constexpr (MODE == 1) rr = z;
    }
#pragma unroll
    for (int c = 0; c < BCH; c++) rb[c] = *(const uint4*)(Brow + k0 + c * 8);
  };
  auto lstore = [&](int buf) {
    v8bf o;
    if constexpr (MODE == 1) {
#pragma unroll
      for (int j = 0; j < 8; j++) o[j] = (__bf16)((float)rh[j] * (float)rr[j]);
    } else {
      o = rh;
    }
    *(v8bf*)(&sA[buf][ar * LDA + ach]) = o;
#pragma unroll
    for (int c = 0; c < BCH; c++)
      *(uint4*)(&sB[buf][br * LDA + bch0 + c * 8]) = rb[c];
  };

  gload(0);
  lstore(0);
  gload(32);
  __syncthreads();

  for (int i = 0; i < 16; i++) {
    v8bf af[MI], bfr[4];
#pragma unroll
    for (int mi = 0; mi < MI; mi++)
      af[mi] = *(const v8bf*)(&sA[i & 1][(wr + mi * 16 + lm) * LDA + quad * 8]);
#pragma unroll
    for (int ni = 0; ni < 4; ni++)
      bfr[ni] = *(const v8bf*)(&sB[i & 1][(wc + ni * 16 + lm) * LDA + quad * 8]);
    if (i + 1 < 16) lstore((i + 1) & 1);
    if (i + 2 < 16) gload((i + 2) * 32);
#pragma unroll
    for (int mi = 0; mi < MI; mi++)
#pragma unroll
      for (int ni = 0; ni < 4; ni++)
        acc4[mi][ni] = __builtin_amdgcn_mfma_f32_16x16x32_bf16(af[mi], bfr[ni], acc4[mi][ni], 0, 0, 0);
    __syncthreads();
  }

  // epilogue
  if constexpr (MODE == 0) {
    __bf16* dst = (col0 < 512) ? Obf : Obf2;
    const int cof = (col0 < 512) ? col0 : col0 - 512;
#pragma unroll
    for (int mi = 0; mi < 4; mi++) {
#pragma unroll
      for (int r = 0; r < 4; r++) {
        int rg = row0 + mi * 16 + quad * 4 + r;
        if (rg >= M) continue;
        const float* yr = Y + (size_t)rg * NF;
        float yv0 = yr[0 * TT + t], yv1 = yr[1 * TT + t];
        float yv2 = yr[2 * TT + t], yv3 = yr[3 * TT + t];
#pragma unroll
        for (int ni = 0; ni < 4; ni++) {
          int cg = col0 + wc + ni * 16 + lm;
          float pre = acc4[mi][ni][r] + beff[cg] + yv0 * Weff[cg] +
                      yv1 * Weff[NoutW + cg] + yv2 * Weff[2 * NoutW + cg] +
                      yv3 * Weff[3 * NoutW + cg];
          float s = 1.f / (1.f + expf(-pre));
          dst[(size_t)rg * 512 + (cof + wc + ni * 16 + lm)] = (__bf16)s;
        }
      }
    }
  } else if constexpr (MODE == 1) {
#pragma unroll
    for (int mi = 0; mi < 2; mi++) {
#pragma unroll
      for (int r = 0; r < 4; r++) {
        int rg = row0 + wr + mi * 16 + quad * 4 + r;
        if (rg >= M) continue;
        const float* yr = Y + (size_t)rg * NF;
        float yv0 = yr[0 * TT + t], yv1 = yr[1 * TT + t];
        float yv2 = yr[2 * TT + t], yv3 = yr[3 * TT + t];
#pragma unroll
        for (int ni = 0; ni < 4; ni++) {
          int cg = col0 + wc + ni * 16 + lm;
          float pre = acc4[mi][ni][r] + beff[cg] + yv0 * Weff[cg] +
                      yv1 * Weff[NoutW + cg] + yv2 * Weff[2 * NoutW + cg] +
                      yv3 * Weff[3 * NoutW + cg];
          float ht = tanhf(pre);
          float z = (float)Zbf[(size_t)rg * 512 + cg];
          float hold = Hold[(size_t)rg * 512 + cg];
          float hn = z * hold + (1.f - z) * ht;
          Ofp[(size_t)rg * 512 + cg] = hn;
          Obf[(size_t)rg * 512 + cg] = (__bf16)hn;
        }
      }
    }
  } else {
#pragma unroll
    for (int mi = 0; mi < 4; mi++) {
#pragma unroll
      for (int r = 0; r < 4; r++) {
        int rg = row0 + mi * 16 + quad * 4 + r;
        if (rg >= M) continue;
#pragma unroll
        for (int ni = 0; ni < 4; ni++) {
          int cg = col0 + wc + ni * 16 + lm;
          float pre = acc4[mi][ni][r] + beff[cg];
          Ofp[(size_t)rg * 256 + cg] = fmaxf(pre, 0.f);
        }
      }
    }
  }
}

// acc[i,c] = sum_t probs[t] * hist[t+1][i,c];  accRelu = bf16(relu(acc))
__global__ void k_acc(const __bf16* __restrict__ hist, const float* __restrict__ probs,
                      float* __restrict__ acc, __bf16* __restrict__ accRelu, int n) {
  int idx = blockIdx.x * blockDim.x + threadIdx.x;
  if (idx >= n * 64) return;
  size_t off = (size_t)idx * 8;
  size_t S = (size_t)n * 512;
  float s[8] = {0, 0, 0, 0, 0, 0, 0, 0};
#pragma unroll
  for (int t = 0; t < TT; t++) {
    float p = probs[t];
    v8bf h = *(const v8bf*)(hist + (size_t)(t + 1) * S + off);
#pragma unroll
    for (int j = 0; j < 8; j++) s[j] = fmaf(p, (float)h[j], s[j]);
  }
  float4 o0 = make_float4(s[0], s[1], s[2], s[3]);
  float4 o1 = make_float4(s[4], s[5], s[6], s[7]);
  *(float4*)(acc + off) = o0;
  *(float4*)(acc + off + 4) = o1;
  v8bf rl;
#pragma unroll
  for (int j = 0; j < 8; j++) rl[j] = (__bf16)fmaxf(s[j], 0.f);
  *(v8bf*)(accRelu + off) = rl;
}

__global__ void k_head2(const float* __restrict__ T1, const float* __restrict__ W2,
                        const float* __restrict__ b2, float* __restrict__ out0, int M) {
  int idx = blockIdx.x * blockDim.x + threadIdx.x;
  if (idx >= M * 12) return;
  int i = idx / 12, c = idx % 12;
  const float* tr = T1 + (size_t)i * 256;
  float s = b2[c];
  for (int k = 0; k < 256; k++) s = fmaf(tr[k], W2[k * 12 + c], s);
  out0[idx] = s;
}

// ---------------- launch ----------------

extern "C" void kernel_launch(void* const* d_in, const int* in_sizes, int n_in,
                              void* d_out, int out_size, void* d_ws, size_t ws_size,
                              hipStream_t stream) {
  const float* x   = (const float*)d_in[0];
  const int*   ei  = (const int*)d_in[1];
  const float* ea  = (const float*)d_in[2];
  const float* att = (const float*)d_in[3];
  const float* Wzg = (const float*)d_in[4];  const float* bzg = (const float*)d_in[5];
  const float* Wzl = (const float*)d_in[6];  const float* bzl = (const float*)d_in[7];
  const float* Wrg = (const float*)d_in[8];  const float* brg = (const float*)d_in[9];
  const float* Wrl = (const float*)d_in[10]; const float* brl = (const float*)d_in[11];
  const float* Whg = (const float*)d_in[12]; const float* bhg = (const float*)d_in[13];
  const float* Whl = (const float*)d_in[14]; const float* bhl = (const float*)d_in[15];
  const float* W1  = (const float*)d_in[16]; const float* b1  = (const float*)d_in[17];
  const float* W2  = (const float*)d_in[18]; const float* b2  = (const float*)d_in[19];

  const int N = in_sizes[0] / NF;
  const int E = in_sizes[1] / 2;
  const int* srcI = ei;
  const int* dstI = ei + E;

  float* out0 = (float*)d_out;                   // [N,12]
  float* accO = (float*)d_out + (size_t)N * 12;  // [N,512] = H_accum (output 1)

  char* wp = (char*)d_ws;
  auto carve = [&](size_t bytes) -> void* {
    void* p = (void*)wp;
    wp += (bytes + 255) & ~(size_t)255;
    return p;
  };
  float*  deg     = (float*)carve((size_t)N * 4);
  float*  dinv    = (float*)carve((size_t)N * 4);
  float*  probs   = (float*)carve(64);
  float*  Y       = (float*)carve((size_t)N * NF * 4);
  __bf16* WzrT    = (__bf16*)carve((size_t)1024 * 512 * 2);
  __bf16* WhT     = (__bf16*)carve((size_t)512 * 512 * 2);
  __bf16* W1T     = (__bf16*)carve((size_t)256 * 512 * 2);
  float*  Wzr_eff = (float*)carve((size_t)4 * 1024 * 4);
  float*  bzr_eff = (float*)carve((size_t)1024 * 4);
  float*  Wh_eff  = (float*)carve((size_t)4 * 512 * 4);
  float*  bh_eff  = (float*)carve((size_t)512 * 4);
  float*  Ha      = (float*)carve((size_t)N * 512 * 4);
  float*  Hb      = (float*)carve((size_t)N * 512 * 4);
  __bf16* hist    = (__bf16*)carve((size_t)(TT + 1) * N * 512 * 2);  // H_0..H_12 bf16
  __bf16* Zbf     = (__bf16*)carve((size_t)N * 512 * 2);
  __bf16* Rbf     = (__bf16*)carve((size_t)N * 512 * 2);
  __bf16* accRelu = (__bf16*)carve((size_t)N * 512 * 2);
  float*  T1      = (float*)carve((size_t)N * 256 * 4);
  int*    cnt     = (int*)carve((size_t)2 * N * 4);  // cnt[N] + fill[N] contiguous
  int*    fill    = cnt + N;
  int*    offs    = (int*)carve((size_t)(N + 1) * 4);
  int*    csrc    = (int*)carve((size_t)E * 4);
  float*  cw      = (float*)carve((size_t)E * 4);
  (void)ws_size; (void)n_in; (void)out_size;

  const int TPB = 256;
  auto cdiv = [](int a, int b) { return (a + b - 1) / b; };
  const size_t S = (size_t)N * 512;

  // degree + normalization
  k_init_deg<<<cdiv(N, TPB), TPB, 0, stream>>>(deg, N);
  k_scatter_deg<<<cdiv(E, TPB), TPB, 0, stream>>>(dstI, ea, deg, E);
  k_dinv<<<cdiv(N, TPB), TPB, 0, stream>>>(deg, dinv, N);

  // CSR by dst, then gather Y = Ahat @ X
  k_zeroi<<<cdiv(2 * N, TPB), TPB, 0, stream>>>(cnt, 2 * N);
  k_count<<<cdiv(E, TPB), TPB, 0, stream>>>(dstI, cnt, E);
  k_scan<<<1, 1024, 0, stream>>>(cnt, offs, N);
  k_place<<<cdiv(E, TPB), TPB, 0, stream>>>(srcI, dstI, ea, offs, fill, csrc, cw, E);
  k_gather<<<cdiv(N * 12, TPB), TPB, 0, stream>>>(offs, csrc, cw, dinv, x, Y, N);

  // weight prep
  k_t_zr<<<cdiv(1024 * 512, TPB), TPB, 0, stream>>>(Wzl, Wrl, WzrT);
  k_t_h<<<cdiv(512 * 512, TPB), TPB, 0, stream>>>(Whl, WhT);
  k_t_1<<<cdiv(256 * 512, TPB), TPB, 0, stream>>>(W1, W1T);
  k_build_eff<<<cdiv(5 * 512, TPB), TPB, 0, stream>>>(Wzg, Wzl, bzg, bzl, Wzr_eff, bzr_eff, 1024, 0);
  k_build_eff<<<cdiv(5 * 512, TPB), TPB, 0, stream>>>(Wrg, Wrl, brg, brl, Wzr_eff, bzr_eff, 1024, 512);
  k_build_eff<<<cdiv(5 * 512, TPB), TPB, 0, stream>>>(Whg, Whl, bhg, bhl, Wh_eff, bh_eff, 512, 0);
  k_softmax_att<<<1, 64, 0, stream>>>(att, probs);

  // init state: H fp32 master and hist slot 0 (bf16) to zero
  k_zero<<<cdiv(N * 512, TPB), TPB, 0, stream>>>(Ha, N * 512);
  k_zeroi<<<cdiv(N * 256, TPB), TPB, 0, stream>>>((int*)hist, N * 256);

  const int gx = cdiv(N, 64);  // 157
  float* Hc = Ha;
  float* Hn = Hb;
  for (int t = 0; t < TT; t++) {
    const __bf16* Hbt = hist + (size_t)t * S;
    __bf16* Hbn = hist + (size_t)(t + 1) * S;
    dim3 g0(gx, 4);
    k_mm<0><<<g0, 256, 0, stream>>>(Hbt, WzrT, nullptr, nullptr, nullptr, Y,
                                    Wzr_eff, bzr_eff, nullptr, Zbf, Rbf, N, t);
    dim3 g1(gx, 4);
    k_mm<1><<<g1, 256, 0, stream>>>(Hbt, WhT, Rbf, Zbf, Hc, Y,
                                    Wh_eff, bh_eff, Hn, Hbn, nullptr, N, t);
    float* tmp = Hc; Hc = Hn; Hn = tmp;
  }

  // H_accum = sum_t p_t H_{t+1}; head
  k_acc<<<cdiv(N * 64, TPB), TPB, 0, stream>>>(hist, probs, accO, accRelu, N);
  dim3 g2(gx, 1);
  k_mm<2><<<g2, 256, 0, stream>>>(accRelu, W1T, nullptr, nullptr, nullptr, nullptr,
                                  nullptr, b1, T1, nullptr, nullptr, N, 0);
  k_head2<<<cdiv(N * 12, TPB), TPB, 0, stream>>>(T1, W2, b2, out0, N);
}

// Round 5
// 1756.011 us; speedup vs baseline: 1.1347x; 1.1347x over previous
//
#include <hip/hip_runtime.h>
#include <math.h>

// F=4, T=12, C=512, HID=256, OUT=12
#define NF 48
#define TT 12

typedef __bf16 v8bf __attribute__((ext_vector_type(8)));
typedef float v4f __attribute__((ext_vector_type(4)));

// ---------------- small prep kernels ----------------

__global__ void k_init_deg(float* __restrict__ deg, int n) {
  int i = blockIdx.x * blockDim.x + threadIdx.x;
  if (i < n) deg[i] = 1.0f;
}

__global__ void k_scatter_deg(const int* __restrict__ dst, const float* __restrict__ w,
                              float* __restrict__ deg, int e) {
  int i = blockIdx.x * blockDim.x + threadIdx.x;
  if (i < e) atomicAdd(&deg[dst[i]], w[i]);
}

__global__ void k_dinv(const float* __restrict__ deg, float* __restrict__ dinv, int n) {
  int i = blockIdx.x * blockDim.x + threadIdx.x;
  if (i < n) dinv[i] = rsqrtf(fmaxf(deg[i], 1e-12f));
}

__global__ void k_zeroi(int* __restrict__ p, int n) {
  int i = blockIdx.x * blockDim.x + threadIdx.x;
  if (i < n) p[i] = 0;
}

// ---------------- CSR build (by dst) ----------------

__global__ void k_count(const int* __restrict__ dst, int* __restrict__ cnt, int e) {
  int i = blockIdx.x * blockDim.x + threadIdx.x;
  if (i < e) atomicAdd(&cnt[dst[i]], 1);
}

__global__ void k_scan(const int* __restrict__ cnt, int* __restrict__ offs, int n) {
  __shared__ int s[1024];
  __shared__ int carry;
  int tid = threadIdx.x;
  if (tid == 0) carry = 0;
  __syncthreads();
  for (int base = 0; base < n; base += 1024) {
    int v = (base + tid < n) ? cnt[base + tid] : 0;
    s[tid] = v;
    __syncthreads();
    for (int off = 1; off < 1024; off <<= 1) {
      int t = 0;
      if (tid >= off) t = s[tid - off];
      __syncthreads();
      s[tid] += t;
      __syncthreads();
    }
    if (base + tid < n) offs[base + tid] = carry + s[tid] - v;
    __syncthreads();
    if (tid == 0) carry += s[1023];
    __syncthreads();
  }
  if (tid == 0) offs[n] = carry;
}

__global__ void k_place(const int* __restrict__ src, const int* __restrict__ dst,
                        const float* __restrict__ w, const int* __restrict__ offs,
                        int* __restrict__ fill, int* __restrict__ csrc,
                        float* __restrict__ cw, int e) {
  int i = blockIdx.x * blockDim.x + threadIdx.x;
  if (i >= e) return;
  int d = dst[i];
  int p = offs[d] + atomicAdd(&fill[d], 1);
  csrc[p] = src[i];
  cw[p] = w[i];
}

__global__ void k_gather(const int* __restrict__ offs, const int* __restrict__ csrc,
                         const float* __restrict__ cw, const float* __restrict__ dinv,
                         const float* __restrict__ x, float* __restrict__ Y, int n) {
  int tg = blockIdx.x * blockDim.x + threadIdx.x;
  if (tg >= n * 12) return;
  int i = tg / 12, q = tg % 12;
  float di = dinv[i];
  const float4* x4 = (const float4*)x;
  float4 sv = x4[(size_t)i * 12 + q];
  float ax = di * sv.x, ay = di * sv.y, az = di * sv.z, aw = di * sv.w;
  int e1 = offs[i + 1];
  for (int e = offs[i]; e < e1; e++) {
    int s = csrc[e];
    float wv = cw[e] * dinv[s];
    float4 xv = x4[(size_t)s * 12 + q];
    ax = fmaf(wv, xv.x, ax); ay = fmaf(wv, xv.y, ay);
    az = fmaf(wv, xv.z, az); aw = fmaf(wv, xv.w, aw);
  }
  float4 o = make_float4(di * ax, di * ay, di * az, di * aw);
  ((float4*)Y)[(size_t)i * 12 + q] = o;
}

// ---------------- weight prep: pack into LDS-tile image ----------------
// pack(n,k,TN): tiles of TN output-cols x 32 k, row-major inside tile.
__device__ __forceinline__ size_t packIdx(int n, int k, int TN) {
  return (size_t)(n / TN) * TN * 512 + (size_t)(k >> 5) * TN * 32 +
         (size_t)(n % TN) * 32 + (k & 31);
}

// [z|r] bottom halves of Wz_l / Wr_l, TN=256
__global__ void k_t_zr(const float* __restrict__ Wzl, const float* __restrict__ Wrl,
                       __bf16* __restrict__ WT) {
  int idx = blockIdx.x * blockDim.x + threadIdx.x;
  if (idx >= 1024 * 512) return;
  int n = idx >> 9, k = idx & 511;
  float v = (n < 512) ? Wzl[(512 + k) * 512 + n] : Wrl[(512 + k) * 512 + (n - 512)];
  WT[packIdx(n, k, 256)] = (__bf16)v;
}

// Wh_l bottom half, TN=128
__global__ void k_t_h(const float* __restrict__ Whl, __bf16* __restrict__ WT) {
  int idx = blockIdx.x * blockDim.x + threadIdx.x;
  if (idx >= 512 * 512) return;
  int n = idx >> 9, k = idx & 511;
  WT[packIdx(n, k, 128)] = (__bf16)Whl[(512 + k) * 512 + n];
}

// W1, TN=256
__global__ void k_t_1(const float* __restrict__ W1, __bf16* __restrict__ WT) {
  int idx = blockIdx.x * blockDim.x + threadIdx.x;
  if (idx >= 256 * 512) return;
  int n = idx >> 9, k = idx & 511;
  WT[packIdx(n, k, 256)] = (__bf16)W1[k * 256 + n];
}

__global__ void k_build_eff(const float* __restrict__ Wg, const float* __restrict__ Wl,
                            const float* __restrict__ bg, const float* __restrict__ bl,
                            float* __restrict__ Weff, float* __restrict__ beff,
                            int ostride, int ooff) {
  int idx = blockIdx.x * blockDim.x + threadIdx.x;
  if (idx >= 5 * 512) return;
  int r = idx / 512, c = idx % 512;
  float s = 0.f;
  if (r < 4) {
    for (int k = 0; k < 512; k++) s += Wg[r * 512 + k] * Wl[k * 512 + c];
    Weff[r * ostride + ooff + c] = s;
  } else {
    for (int k = 0; k < 512; k++) s += bg[k] * Wl[k * 512 + c];
    beff[ooff + c] = s + bl[c];
  }
}

__global__ void k_softmax_att(const float* __restrict__ att, float* __restrict__ probs) {
  if (blockIdx.x == 0 && threadIdx.x == 0) {
    float m = -1e30f;
    for (int t = 0; t < TT; t++) m = fmaxf(m, att[t]);
    float e[TT], s = 0.f;
    for (int t = 0; t < TT; t++) { e[t] = expf(att[t] - m); s += e[t]; }
    for (int t = 0; t < TT; t++) probs[t] = e[t] / s;
  }
}

// ---------------- MFMA GEMM, pipelined ----------------
// C = A[M,512]bf16 @ Bp^T (Bp packed tiles). 64-row tiles, BK=32, dbuf LDS,
// 1 barrier/iter. B loads 1 iter ahead (L2-hot), A loads 3-slot / 2 iters ahead (HBM).
// MODE 0: 64x256. epi: sigmoid(pre+Y@Weff+beff) -> z (cols<512) / r (cols>=512), bf16
// MODE 1: 64x128. A-staging multiplies by r. epi: ht=tanh(..); hn=z*hold+(1-z)*ht -> hist bf16
// MODE 2: 64x256. A=accRelu. epi: relu(pre+b1) -> T1 fp32
template <int MODE>
__global__ __launch_bounds__(256, 2) void k_mm(
    const __bf16* __restrict__ Abf, const __bf16* __restrict__ Bp,
    const __bf16* __restrict__ Rbf, const __bf16* __restrict__ Zbf,
    const float* __restrict__ Y, const float* __restrict__ Weff,
    const float* __restrict__ beff,
    float* __restrict__ Ofp, __bf16* __restrict__ Obf, __bf16* __restrict__ Obf2,
    int M, int t) {
  constexpr int TN = (MODE == 1) ? 128 : 256;
  constexpr int NoutW = (MODE == 0) ? 1024 : 512;
  constexpr int BCH = TN * 32 / (256 * 8);  // 4 (MODE0/2) or 2 (MODE1)
  constexpr int MI = (MODE == 1) ? 2 : 4;
  __shared__ __bf16 sA[2][64 * 40];
  __shared__ __bf16 sB[2][TN * 40];
  const int tid = threadIdx.x;
  const int row0 = blockIdx.y * 64;
  const int col0 = blockIdx.x * TN;
  const int w = tid >> 6, lane = tid & 63, lm = lane & 15, quad = lane >> 4;
  const int wr = (MODE == 1) ? (w >> 1) * 32 : 0;
  const int wc = (MODE == 1) ? (w & 1) * 64 : w * 64;

  // A staging: thread -> (row ar, 16B chunk ach)
  const int ar = tid >> 2, ach = (tid & 3) * 8;
  const int arg = row0 + ar;
  const bool aval = arg < M;
  const __bf16* Arow = Abf + (size_t)arg * 512 + ach;
  const __bf16* Rrow = Rbf + (size_t)arg * 512 + ach;  // MODE1 only
  // B staging: packed, fully coalesced; LDS row = j*64 + tid/4
  const __bf16* Bbase = Bp + (size_t)col0 * 512;

  v4f acc4[MI][4];
#pragma unroll
  for (int i = 0; i < MI; i++)
#pragma unroll
    for (int j = 0; j < 4; j++) acc4[i][j] = (v4f){0.f, 0.f, 0.f, 0.f};

  v8bf zero8;
#pragma unroll
  for (int j = 0; j < 8; j++) zero8[j] = (__bf16)0.f;

  v8bf rhS[3], rrS[3];
  uint4 rb[BCH];
  (void)rrS;

  auto gloadA = [&](int tile, int slot) {
    if (aval) {
      rhS[slot] = *(const v8bf*)(Arow + tile * 32);
      if constexpr (MODE == 1) rrS[slot] = *(const v8bf*)(Rrow + tile * 32);
    } else {
      rhS[slot] = zero8;
      if constexpr (MODE == 1) rrS[slot] = zero8;
    }
  };
  auto gloadB = [&](int tile) {
    const __bf16* tb = Bbase + (size_t)tile * TN * 32;
#pragma unroll
    for (int c = 0; c < BCH; c++)
      rb[c] = *(const uint4*)(tb + (size_t)(c * 256 + tid) * 8);
  };
  auto lstore = [&](int slot, int buf) {
    v8bf o;
    if constexpr (MODE == 1) {
#pragma unroll
      for (int j = 0; j < 8; j++)
        o[j] = (__bf16)((float)rhS[slot][j] * (float)rrS[slot][j]);
    } else {
      o = rhS[slot];
    }
    *(v8bf*)(&sA[buf][ar * 40 + ach]) = o;
#pragma unroll
    for (int c = 0; c < BCH; c++)
      *(uint4*)(&sB[buf][(c * 64 + (tid >> 2)) * 40 + (tid & 3) * 8]) = rb[c];
  };

  // preamble: tiles 0,1,2 of A in flight; tile0 stored; tile1 B in regs
  gloadA(0, 0);
  gloadA(1, 1);
  gloadB(0);
  lstore(0, 0);
  gloadB(1);
  gloadA(2, 2);
  __syncthreads();

#pragma unroll
  for (int i = 0; i < 16; i++) {
    v8bf af[MI], bfr[4];
#pragma unroll
    for (int mi = 0; mi < MI; mi++)
      af[mi] = *(const v8bf*)(&sA[i & 1][(wr + mi * 16 + lm) * 40 + quad * 8]);
#pragma unroll
    for (int ni = 0; ni < 4; ni++)
      bfr[ni] = *(const v8bf*)(&sB[i & 1][(wc + ni * 16 + lm) * 40 + quad * 8]);
    if (i + 1 < 16) lstore((i + 1) % 3, (i + 1) & 1);
    if (i + 2 < 16) gloadB(i + 2);
    if (i + 3 < 16) gloadA(i + 3, (i + 3) % 3);
#pragma unroll
    for (int mi = 0; mi < MI; mi++)
#pragma unroll
      for (int ni = 0; ni < 4; ni++)
        acc4[mi][ni] = __builtin_amdgcn_mfma_f32_16x16x32_bf16(af[mi], bfr[ni], acc4[mi][ni], 0, 0, 0);
    __syncthreads();
  }

  // epilogue
  if constexpr (MODE == 0) {
    __bf16* dst = (col0 < 512) ? Obf : Obf2;
    const int cof = (col0 < 512) ? col0 : col0 - 512;
#pragma unroll
    for (int mi = 0; mi < 4; mi++) {
#pragma unroll
      for (int r = 0; r < 4; r++) {
        int rg = row0 + mi * 16 + quad * 4 + r;
        if (rg >= M) continue;
        const float* yr = Y + (size_t)rg * NF;
        float yv0 = yr[0 * TT + t], yv1 = yr[1 * TT + t];
        float yv2 = yr[2 * TT + t], yv3 = yr[3 * TT + t];
#pragma unroll
        for (int ni = 0; ni < 4; ni++) {
          int cg = col0 + wc + ni * 16 + lm;
          float pre = acc4[mi][ni][r] + beff[cg] + yv0 * Weff[cg] +
                      yv1 * Weff[NoutW + cg] + yv2 * Weff[2 * NoutW + cg] +
                      yv3 * Weff[3 * NoutW + cg];
          float s = 1.f / (1.f + expf(-pre));
          dst[(size_t)rg * 512 + (cof + wc + ni * 16 + lm)] = (__bf16)s;
        }
      }
    }
  } else if constexpr (MODE == 1) {
#pragma unroll
    for (int mi = 0; mi < 2; mi++) {
#pragma unroll
      for (int r = 0; r < 4; r++) {
        int rg = row0 + wr + mi * 16 + quad * 4 + r;
        if (rg >= M) continue;
        const float* yr = Y + (size_t)rg * NF;
        float yv0 = yr[0 * TT + t], yv1 = yr[1 * TT + t];
        float yv2 = yr[2 * TT + t], yv3 = yr[3 * TT + t];
#pragma unroll
        for (int ni = 0; ni < 4; ni++) {
          int cg = col0 + wc + ni * 16 + lm;
          float pre = acc4[mi][ni][r] + beff[cg] + yv0 * Weff[cg] +
                      yv1 * Weff[NoutW + cg] + yv2 * Weff[2 * NoutW + cg] +
                      yv3 * Weff[3 * NoutW + cg];
          float ht = tanhf(pre);
          float z = (float)Zbf[(size_t)rg * 512 + cg];
          float hold = (float)Abf[(size_t)rg * 512 + cg];
          float hn = z * hold + (1.f - z) * ht;
          Obf[(size_t)rg * 512 + cg] = (__bf16)hn;
        }
      }
    }
  } else {
#pragma unroll
    for (int mi = 0; mi < 4; mi++) {
#pragma unroll
      for (int r = 0; r < 4; r++) {
        int rg = row0 + mi * 16 + quad * 4 + r;
        if (rg >= M) continue;
#pragma unroll
        for (int ni = 0; ni < 4; ni++) {
          int cg = col0 + wc + ni * 16 + lm;
          float pre = acc4[mi][ni][r] + beff[cg];
          Ofp[(size_t)rg * 256 + cg] = fmaxf(pre, 0.f);
        }
      }
    }
  }
}

// acc[i,c] = sum_t probs[t] * hist[t+1][i,c];  accRelu = bf16(relu(acc))
__global__ void k_acc(const __bf16* __restrict__ hist, const float* __restrict__ probs,
                      float* __restrict__ acc, __bf16* __restrict__ accRelu, int n) {
  int idx = blockIdx.x * blockDim.x + threadIdx.x;
  if (idx >= n * 64) return;
  size_t off = (size_t)idx * 8;
  size_t S = (size_t)n * 512;
  float s[8] = {0, 0, 0, 0, 0, 0, 0, 0};
#pragma unroll
  for (int t = 0; t < TT; t++) {
    float p = probs[t];
    v8bf h = *(const v8bf*)(hist + (size_t)(t + 1) * S + off);
#pragma unroll
    for (int j = 0; j < 8; j++) s[j] = fmaf(p, (float)h[j], s[j]);
  }
  *(float4*)(acc + off) = make_float4(s[0], s[1], s[2], s[3]);
  *(float4*)(acc + off + 4) = make_float4(s[4], s[5], s[6], s[7]);
  v8bf rl;
#pragma unroll
  for (int j = 0; j < 8; j++) rl[j] = (__bf16)fmaxf(s[j], 0.f);
  *(v8bf*)(accRelu + off) = rl;
}

__global__ void k_head2(const float* __restrict__ T1, const float* __restrict__ W2,
                        const float* __restrict__ b2, float* __restrict__ out0, int M) {
  int idx = blockIdx.x * blockDim.x + threadIdx.x;
  if (idx >= M * 12) return;
  int i = idx / 12, c = idx % 12;
  const float* tr = T1 + (size_t)i * 256;
  float s = b2[c];
  for (int k = 0; k < 256; k++) s = fmaf(tr[k], W2[k * 12 + c], s);
  out0[idx] = s;
}

// ---------------- launch ----------------

extern "C" void kernel_launch(void* const* d_in, const int* in_sizes, int n_in,
                              void* d_out, int out_size, void* d_ws, size_t ws_size,
                              hipStream_t stream) {
  const float* x   = (const float*)d_in[0];
  const int*   ei  = (const int*)d_in[1];
  const float* ea  = (const float*)d_in[2];
  const float* att = (const float*)d_in[3];
  const float* Wzg = (const float*)d_in[4];  const float* bzg = (const float*)d_in[5];
  const float* Wzl = (const float*)d_in[6];  const float* bzl = (const float*)d_in[7];
  const float* Wrg = (const float*)d_in[8];  const float* brg = (const float*)d_in[9];
  const float* Wrl = (const float*)d_in[10]; const float* brl = (const float*)d_in[11];
  const float* Whg = (const float*)d_in[12]; const float* bhg = (const float*)d_in[13];
  const float* Whl = (const float*)d_in[14]; const float* bhl = (const float*)d_in[15];
  const float* W1  = (const float*)d_in[16]; const float* b1  = (const float*)d_in[17];
  const float* W2  = (const float*)d_in[18]; const float* b2  = (const float*)d_in[19];

  const int N = in_sizes[0] / NF;
  const int E = in_sizes[1] / 2;
  const int* srcI = ei;
  const int* dstI = ei + E;

  float* out0 = (float*)d_out;                   // [N,12]
  float* accO = (float*)d_out + (size_t)N * 12;  // [N,512] = H_accum (output 1)

  char* wp = (char*)d_ws;
  auto carve = [&](size_t bytes) -> void* {
    void* p = (void*)wp;
    wp += (bytes + 255) & ~(size_t)255;
    return p;
  };
  float*  deg     = (float*)carve((size_t)N * 4);
  float*  dinv    = (float*)carve((size_t)N * 4);
  float*  probs   = (float*)carve(64);
  float*  Y       = (float*)carve((size_t)N * NF * 4);
  __bf16* WzrP    = (__bf16*)carve((size_t)1024 * 512 * 2);
  __bf16* WhP     = (__bf16*)carve((size_t)512 * 512 * 2);
  __bf16* W1P     = (__bf16*)carve((size_t)256 * 512 * 2);
  float*  Wzr_eff = (float*)carve((size_t)4 * 1024 * 4);
  float*  bzr_eff = (float*)carve((size_t)1024 * 4);
  float*  Wh_eff  = (float*)carve((size_t)4 * 512 * 4);
  float*  bh_eff  = (float*)carve((size_t)512 * 4);
  __bf16* hist    = (__bf16*)carve((size_t)(TT + 1) * N * 512 * 2);  // H_0..H_12 bf16
  __bf16* Zbf     = (__bf16*)carve((size_t)N * 512 * 2);
  __bf16* Rbf     = (__bf16*)carve((size_t)N * 512 * 2);
  __bf16* accRelu = (__bf16*)carve((size_t)N * 512 * 2);
  float*  T1      = (float*)carve((size_t)N * 256 * 4);
  int*    cnt     = (int*)carve((size_t)2 * N * 4);  // cnt[N] + fill[N] contiguous
  int*    fill    = cnt + N;
  int*    offs    = (int*)carve((size_t)(N + 1) * 4);
  int*    csrc    = (int*)carve((size_t)E * 4);
  float*  cw      = (float*)carve((size_t)E * 4);
  (void)ws_size; (void)n_in; (void)out_size;

  const int TPB = 256;
  auto cdiv = [](int a, int b) { return (a + b - 1) / b; };
  const size_t S = (size_t)N * 512;

  // degree + normalization
  k_init_deg<<<cdiv(N, TPB), TPB, 0, stream>>>(deg, N);
  k_scatter_deg<<<cdiv(E, TPB), TPB, 0, stream>>>(dstI, ea, deg, E);
  k_dinv<<<cdiv(N, TPB), TPB, 0, stream>>>(deg, dinv, N);

  // CSR by dst, then gather Y = Ahat @ X
  k_zeroi<<<cdiv(2 * N, TPB), TPB, 0, stream>>>(cnt, 2 * N);
  k_count<<<cdiv(E, TPB), TPB, 0, stream>>>(dstI, cnt, E);
  k_scan<<<1, 1024, 0, stream>>>(cnt, offs, N);
  k_place<<<cdiv(E, TPB), TPB, 0, stream>>>(srcI, dstI, ea, offs, fill, csrc, cw, E);
  k_gather<<<cdiv(N * 12, TPB), TPB, 0, stream>>>(offs, csrc, cw, dinv, x, Y, N);

  // weight prep (packed bf16 tiles) + folded GCN weights
  k_t_zr<<<cdiv(1024 * 512, TPB), TPB, 0, stream>>>(Wzl, Wrl, WzrP);
  k_t_h<<<cdiv(512 * 512, TPB), TPB, 0, stream>>>(Whl, WhP);
  k_t_1<<<cdiv(256 * 512, TPB), TPB, 0, stream>>>(W1, W1P);
  k_build_eff<<<cdiv(5 * 512, TPB), TPB, 0, stream>>>(Wzg, Wzl, bzg, bzl, Wzr_eff, bzr_eff, 1024, 0);
  k_build_eff<<<cdiv(5 * 512, TPB), TPB, 0, stream>>>(Wrg, Wrl, brg, brl, Wzr_eff, bzr_eff, 1024, 512);
  k_build_eff<<<cdiv(5 * 512, TPB), TPB, 0, stream>>>(Whg, Whl, bhg, bhl, Wh_eff, bh_eff, 512, 0);
  k_softmax_att<<<1, 64, 0, stream>>>(att, probs);

  // hist slot 0 = H_0 = 0
  k_zeroi<<<cdiv(N * 256, TPB), TPB, 0, stream>>>((int*)hist, N * 256);

  const int gy = cdiv(N, 64);  // 157 row blocks
  for (int t = 0; t < TT; t++) {
    const __bf16* Hbt = hist + (size_t)t * S;
    __bf16* Hbn = hist + (size_t)(t + 1) * S;
    dim3 g0(4, gy);
    k_mm<0><<<g0, 256, 0, stream>>>(Hbt, WzrP, nullptr, nullptr, Y,
                                    Wzr_eff, bzr_eff, nullptr, Zbf, Rbf, N, t);
    dim3 g1(4, gy);
    k_mm<1><<<g1, 256, 0, stream>>>(Hbt, WhP, Rbf, Zbf, Y,
                                    Wh_eff, bh_eff, nullptr, Hbn, nullptr, N, t);
  }

  // H_accum = sum_t p_t H_{t+1}; head
  k_acc<<<cdiv(N * 64, TPB), TPB, 0, stream>>>(hist, probs, accO, accRelu, N);
  dim3 g2(1, gy);
  k_mm<2><<<g2, 256, 0, stream>>>(accRelu, W1P, nullptr, nullptr, nullptr,
                                  nullptr, b1, T1, nullptr, nullptr, N, 0);
  k_head2<<<cdiv(N * 12, TPB), TPB, 0, stream>>>(T1, W2, b2, out0, N);
}